// Round 12
// baseline (172.913 us; speedup 1.0000x reference)
//
#include <hip/hip_runtime.h>
#include <hip/hip_bf16.h>

#define NCOLS 16384
#define DDIM  256
#define SQRT_L2E 1.2011224087864498f  // sqrt(log2 e); A*B picks up log2(e)

typedef __attribute__((ext_vector_type(8))) short bf16x8;
typedef __attribute__((ext_vector_type(4))) float f32x4;
typedef __attribute__((ext_vector_type(4))) int   i32x4;

typedef __attribute__((address_space(1))) const unsigned int gu32;
typedef __attribute__((address_space(3))) unsigned int       lu32;

static __device__ __forceinline__ ushort f2bf_rne(float f) {
    unsigned u = __builtin_bit_cast(unsigned, f);
    unsigned r = (u + 0x7fffu + ((u >> 16) & 1u)) >> 16;
    return (ushort)r;
}

// ---- Kernel 1: single-pass column norm + scale + bf16 pack (transposed out).
__global__ __launch_bounds__(256)
void k_norm(const float* __restrict__ W, ushort* __restrict__ wnT,
            float* __restrict__ S) {
    __shared__ float red[8][32];
    __shared__ float scale_s[32];
    const int tid = threadIdx.x;
    const int il = tid & 31, st = tid >> 5;
    const int col = blockIdx.x * 32 + il;
    float v[32];
    float p = 0.f;
    #pragma unroll
    for (int e = 0; e < 32; ++e) {
        v[e] = W[(size_t)(st * 32 + e) * NCOLS + col];
        p = fmaf(v[e], v[e], p);
    }
    red[st][il] = p;
    __syncthreads();
    if (tid < 32) {
        float n = 0.f;
        #pragma unroll
        for (int q = 0; q < 8; ++q) n += red[q][tid];
        scale_s[tid] = SQRT_L2E / fmaxf(sqrtf(n), 1e-8f);
        S[blockIdx.x * 32 + tid] = 0.f;          // zero row-sum accumulator
    }
    __syncthreads();
    const float sc = scale_s[il];
    #pragma unroll
    for (int g = 0; g < 4; ++g) {
        union { ushort us[8]; i32x4 w4; } pk;
        #pragma unroll
        for (int e2 = 0; e2 < 8; ++e2) pk.us[e2] = f2bf_rne(v[g * 8 + e2] * sc);
        *reinterpret_cast<i32x4*>(&wnT[(size_t)col * DDIM + st * 32 + g * 8]) = pk.w4;
    }
}

// ---- Kernel 2: symmetric Gram + exp + row/col sums, strip-sweep +
// counted-vmcnt triple-buffer pipeline (T3/T4) + XCD super-row affinity.
// Super-row sr pairs strips {sr,127-sr}: 516 sub-tiles in 8 chunks
// (65,65,65,65,64,64,64,64). Grid 512 = exactly 2 blocks/CU (zero tail).
// Pipeline: prefetch depth 2 into Bs[3]; per-iter s_waitcnt vmcnt(4) keeps
// the newest stage's 4 loads in flight across the barrier (never vmcnt(0)).
// Barrier BEFORE stage: buffer (q+2)%3 was last read at iter q-1; the
// barrier proves all waves finished q-1 before anyone overwrites it.
__global__ __launch_bounds__(256, 3)
void k_gram(const ushort* __restrict__ wnT, float* __restrict__ S) {
    __shared__ ushort Bs[3][32 * DDIM];          // 3 x 16 KiB
    __shared__ float colAcc[65 * 32];            // 8.3 KiB (block col partials)

    const int bid = blockIdx.x;
    const int x   = bid & 7;                     // XCD id (round-robin)
    const int idx = bid >> 3;
    const int sr  = x + 8 * (idx >> 3);          // sr ≡ XCD (mod 8): A L2-resident
    const int cch = idx & 7;
    const int rowA = sr, rowB = 127 - sr;
    const int La  = 512 - 4 * rowA;              // sub-tiles in strip A
    const int cnt = 64 + (cch < 4 ? 1 : 0);      // 4*65 + 4*64 = 516
    const int p0  = cch * 64 + (cch < 4 ? cch : 4);

    const int tid  = threadIdx.x;
    const int lane = tid & 63, wave = tid >> 6;
    const int l15  = lane & 15;
    const int kq16 = ((lane >> 4) & 3) * 16;     // k-quad byte offset
    const int xorm = (lane & 7) << 4;            // read-side swizzle

    for (int o = tid; o < 65 * 32; o += 256) colAcc[o] = 0.f;

    bf16x8 afrag[2][8];
    float rowsum[2][4];

    auto load_a = [&](int rowt) {
        const int i0 = rowt * 128;
        #pragma unroll
        for (int s = 0; s < 2; ++s) {
            const ushort* arow = wnT +
                (size_t)(i0 + wave * 32 + s * 16 + l15) * DDIM + (kq16 >> 1);
            #pragma unroll
            for (int kk = 0; kk < 8; ++kk)
                afrag[s][kk] = *reinterpret_cast<const bf16x8*>(arow + kk * 32);
        }
    };
    auto zero_rows = [&]() {
        #pragma unroll
        for (int s = 0; s < 2; ++s)
            #pragma unroll
            for (int r = 0; r < 4; ++r) rowsum[s][r] = 0.f;
    };
    auto flush_rows = [&](int i0) {   // C layout: col=lane&15, row=(lane>>4)*4+r
        #pragma unroll
        for (int s = 0; s < 2; ++s)
            #pragma unroll
            for (int r = 0; r < 4; ++r) {
                float v = rowsum[s][r];
                v += __shfl_xor(v, 1, 64);
                v += __shfl_xor(v, 2, 64);
                v += __shfl_xor(v, 4, 64);
                v += __shfl_xor(v, 8, 64);
                if (l15 == 0)
                    atomicAdd(&S[i0 + wave * 32 + s * 16 + (lane >> 4) * 4 + r], v);
            }
    };
    auto stage = [&](int b, int p) {   // rule #21: linear dest, inv-swz source
        const bool inA = (p < La);
        const int prow = inA ? rowA : rowB;
        const int pk   = inA ? p : p - La;
        const int j0   = prow * 128 + pk * 32;
        #pragma unroll
        for (int qq = 0; qq < 4; ++qq) {
            const int r0 = wave * 8 + qq * 2;
            const int rl = r0 + (lane >> 5);
            const int sb = ((lane & 31) * 16) ^ ((rl & 7) << 4);
            const ushort* g = wnT + (size_t)(j0 + rl) * DDIM + (sb >> 1);
            char* l = (char*)&Bs[b][0] + (r0 << 9);   // wave-uniform dest
            __builtin_amdgcn_global_load_lds((gu32*)g, (lu32*)l, 16, 0, 0);
        }
    };

    int crow = (p0 < La) ? rowA : rowB;
    load_a(crow);
    zero_rows();
    stage(0, p0);
    stage(1, p0 + 1);

    for (int q = 0; q < cnt; ++q) {
        const int p = p0 + q;
        // in-order vmcnt: <=4 outstanding ==> stage(q)'s loads retired;
        // stage(q+1)'s 4 remain in flight across the barrier.
        asm volatile("s_waitcnt vmcnt(4)" ::: "memory");
        __builtin_amdgcn_s_barrier();
        if (q > 0 && p == La) {                  // row-strip crossing (once max)
            flush_rows(rowA * 128);
            zero_rows();
            load_a(rowB);
            crow = rowB;
        }
        if (q + 2 < cnt) stage((q + 2) % 3, p + 2);

        const char* bufbase = (const char*)&Bs[q % 3][0];
        float colp0 = 0.f, colp1 = 0.f;
        #pragma unroll
        for (int jj = 0; jj < 2; ++jj) {
            const char* brow = bufbase + ((jj * 16 + l15) << 9);
            bf16x8 b[8];
            #pragma unroll
            for (int kk = 0; kk < 8; ++kk)
                b[kk] = *reinterpret_cast<const bf16x8*>(
                    brow + ((kk * 64 + kq16) ^ xorm));
            __builtin_amdgcn_s_setprio(1);
            #pragma unroll
            for (int s = 0; s < 2; ++s) {
                f32x4 acc = {0.f, 0.f, 0.f, 0.f};
                #pragma unroll
                for (int kk = 0; kk < 8; ++kk)
                    acc = __builtin_amdgcn_mfma_f32_16x16x32_bf16(
                        afrag[s][kk], b[kk], acc, 0, 0, 0);
                __builtin_amdgcn_s_setprio(0);
                #pragma unroll
                for (int r = 0; r < 4; ++r) {
                    float e = __builtin_amdgcn_exp2f(acc[r]);   // = exp(G)
                    rowsum[s][r] += e;
                    if (jj == 0) colp0 += e; else colp1 += e;
                }
                __builtin_amdgcn_s_setprio(1);
            }
            __builtin_amdgcn_s_setprio(0);
        }
        // col partials: reduce over 4 row-groups, LDS-atomic into colAcc
        {
            float v = colp0;
            v += __shfl_xor(v, 16, 64);
            v += __shfl_xor(v, 32, 64);
            if (lane < 16) atomicAdd(&colAcc[q * 32 + l15], v);
            float w = colp1;
            w += __shfl_xor(w, 16, 64);
            w += __shfl_xor(w, 32, 64);
            if (lane < 16) atomicAdd(&colAcc[q * 32 + 16 + l15], w);
        }
    }
    flush_rows(crow * 128);
    __syncthreads();                 // colAcc ds-atomics visible to all waves
    // mirrored col flush (skip sub-tiles inside the diagonal 128x128 tile)
    for (int o = tid; o < cnt * 32; o += 256) {
        const int qq = o >> 5, cc = o & 31;
        const int p = p0 + qq;
        const bool inA = (p < La);
        const int prow = inA ? rowA : rowB;
        const int pk   = inA ? p : p - La;
        if (pk >= 4) atomicAdd(&S[prow * 128 + pk * 32 + cc], colAcc[o]);
    }
}

// ---- Kernel 3: loss = lw * (ln2 * sum(log2 S) - N) / N   (the -1 folded here)
__global__ __launch_bounds__(1024)
void k_final(const float* __restrict__ S, const float* __restrict__ lw,
             float* __restrict__ out) {
    float a = 0.f;
    for (int i = threadIdx.x; i < NCOLS; i += 1024)
        a += __builtin_amdgcn_logf(S[i]);          // log2
    #pragma unroll
    for (int m2 = 1; m2 < 64; m2 <<= 1) a += __shfl_xor(a, m2, 64);
    __shared__ float red[16];
    if ((threadIdx.x & 63) == 0) red[threadIdx.x >> 6] = a;
    __syncthreads();
    if (threadIdx.x == 0) {
        float tot = 0.f;
        #pragma unroll
        for (int q2 = 0; q2 < 16; ++q2) tot += red[q2];
        out[0] = lw[0] * (tot * 0.6931471805599453f - (float)NCOLS) / (float)NCOLS;
    }
}

extern "C" void kernel_launch(void* const* d_in, const int* in_sizes, int n_in,
                              void* d_out, int out_size, void* d_ws, size_t ws_size,
                              hipStream_t stream) {
    const float* W  = (const float*)d_in[0];
    const float* lw = (const float*)d_in[1];
    float* out = (float*)d_out;

    ushort* wnT = (ushort*)d_ws;                                    // 8 MiB
    float*  S   = (float*)((char*)d_ws + (size_t)NCOLS * DDIM * 2); // 64 KiB

    k_norm <<<NCOLS / 32, 256, 0, stream>>>(W, wnT, S);
    k_gram <<<512, 256, 0, stream>>>(wnT, S);
    k_final<<<1, 1024, 0, stream>>>(S, lw, out);
}